// Round 6
// baseline (1626.864 us; speedup 1.0000x reference)
//
#include <hip/hip_runtime.h>
#include <hip/hip_fp16.h>

typedef _Float16 half8 __attribute__((ext_vector_type(8)));
typedef float floatx4 __attribute__((ext_vector_type(4)));

#define T_STEPS 30
#define BATCH   256
#define HID     1024
#define LAYERS  4
#define N4H     4096
#define K2      2048

#define BM 128
#define BN 128
#define BKH 64      // K per half per iteration
#define KITERS 16   // 1024 / BKH
#define ZLD 132     // zs row stride (f32), multiple of 4 for float4 reads

#define AS1(p) ((const __attribute__((address_space(1))) void*)(p))
#define AS3(p) ((__attribute__((address_space(3))) void*)(p))

// ---------- one-time prep: weights [L][H][4H] f32 -> WRt [L][4096 q][2048 k] f16
// q = 4n + gate; W in k[0,1024), R in k[1024,2048).
// v4: two 64x64 k-tiles per block (8 float4 loads in flight), volatile scalar
// LDS stores (prevents misaligned ds_write_b128 merge -> 2-way banks, free).
__global__ void transpose_weights(const float* __restrict__ src_all,
                                  _Float16* __restrict__ wrt, int mat) {
    __shared__ float tile[2][64][65];
    const int j = blockIdx.z;
    const float* src = src_all + (size_t)j * HID * N4H;
    _Float16* dst = wrt + (size_t)j * N4H * K2 + mat * HID;
    const int c0 = blockIdx.x * 64;     // source column tile (over 4H)
    const int k0 = blockIdx.y * 128;    // source row pair-tile (over H = k dim)
    const int t = threadIdx.x;          // 256 flat
    const int c4 = (t & 15) * 4, lr = t >> 4;
    #pragma unroll
    for (int tt = 0; tt < 2; ++tt)
        #pragma unroll
        for (int i = 0; i < 4; ++i) {
            const float4 v = *(const float4*)(src + (size_t)(k0 + tt * 64 + lr + i * 16) * N4H + c0 + c4);
            volatile float* tw = &tile[tt][lr + i * 16][c4];
            tw[0] = v.x; tw[1] = v.y; tw[2] = v.z; tw[3] = v.w;
        }
    __syncthreads();
    const int kg = t & 7, cl0 = t >> 3;   // 8 k-granules x 32 c-lanes
    #pragma unroll
    for (int tt = 0; tt < 2; ++tt)
        #pragma unroll
        for (int i = 0; i < 2; ++i) {
            const int cp = cl0 + i * 32;
            const int c = c0 + cp;
            const int q = ((c & (HID - 1)) << 2) | (c >> 10); // q = 4n + gate
            half8 v;
            #pragma unroll
            for (int jj = 0; jj < 8; ++jj)
                v[jj] = (_Float16)tile[tt][kg * 8 + jj][cp];
            *(half8*)(dst + (size_t)q * K2 + k0 + tt * 64 + kg * 8) = v;
        }
}

// ---------- inputs f32 -> f16
__global__ void cvt_inputs(const float* __restrict__ in, _Float16* __restrict__ out) {
    const size_t i = ((size_t)blockIdx.x * 256 + threadIdx.x) * 8;
    const float4 a = *(const float4*)(in + i);
    const float4 b = *(const float4*)(in + i + 4);
    half8 v;
    v[0] = (_Float16)a.x; v[1] = (_Float16)a.y; v[2] = (_Float16)a.z; v[3] = (_Float16)a.w;
    v[4] = (_Float16)b.x; v[5] = (_Float16)b.y; v[6] = (_Float16)b.z; v[7] = (_Float16)b.w;
    *(half8*)(out + i) = v;
}

// ---------- diagonal-batched fused LSTM cells, v5
// 512 threads = 8 waves. Block tile 128m x 128n. K=2048 split across wave
// halves (waves 0-3: X@W k[0,1024); waves 4-7: H@R k[1024,2048)); partials
// combined in zs. Each wave: 64x64 sub-tile (4x4 of 16x16x32 MFMA).
//
// v5 staging is K-MAJOR: LDS tile layout [8 granules][128 rows] x 16 B, so
// load slot s -> (gl = s>>7, r = s&127). Loads 0-3 of a tile deliver k-slice
// 0 (granules 0-3) for ALL rows; loads 4-7 deliver k-slice 1. Fragment reads
// are 256 B-contiguous per 16 lanes -> conflict-free, no XOR swizzle needed.
//
// K-loop is a 2-phase counted-vmcnt pipeline (T3/T4, m201/m218 pattern):
// per phase {vmcnt(4) -> raw s_barrier -> sched_barrier(0) -> issue next
// tile's half-stage (4 loads) -> 16 MFMA}. Own-vmcnt never drains below 4
// in the main loop, so the L3 fetch stream never goes idle (vs the old
// per-iter vmcnt(0) drain at __syncthreads). Ledger: 8 outstanding at each
// wait; in-order completion means the remaining 4 are the newest half-stage,
// i.e. the awaited half-tile has landed. Barrier then extends this to all
// waves. Buffer WAR safety: a wave issues tile ts+2's loads (into buf cur)
// only after the phase barrier that all waves reach having completed their
// ds_reads of buf cur.
__global__ __launch_bounds__(512) void lstm_diag(
    const _Float16* __restrict__ Xf,      // [30][256][1024] f16
    _Float16*       __restrict__ c_act,   // [2 parity][4][256][1024] f16
    _Float16*       __restrict__ h_act,   // [4][256][1024] f16
    const _Float16* __restrict__ WRt,     // [4][4096][2048] f16
    const float*    __restrict__ bias,    // [4][4096] f32 gate-major
    float*          __restrict__ c_master,// [4][256][1024] f32
    int diag, int packed_t, int packed_j)
{
    const int z = blockIdx.z;
    const int t = (packed_t >> (8 * z)) & 255;
    const int j = (packed_j >> (8 * z)) & 255;
    const size_t BH = (size_t)BATCH * HID;

    const _Float16* X    = (j == 0) ? (Xf + (size_t)t * BH)
                                    : (c_act + ((size_t)((diag - 1) & 1) * LAYERS + (j - 1)) * BH);
    const _Float16* Hrec = h_act + (size_t)j * BH;
    const _Float16* WR   = WRt + (size_t)j * N4H * K2;
    const float* bias_j  = bias + (size_t)j * N4H;
    float* c_m           = c_master + (size_t)j * BH;
    _Float16* c_out      = c_act + ((size_t)(diag & 1) * LAYERS + j) * BH;
    _Float16* h_out      = h_act + (size_t)j * BH;

    // LDS: 2 stage buffers x 64 KiB. Per buffer, per half h:
    //   A_h [8 gl][128 r] f16x8 (16 KiB) | B_h [8 gl][128 q] f16x8 (16 KiB).
    // zs (128 x ZLD f32 = 67584 B) overlays the buffers after the K loop.
    __shared__ __align__(16) char smem[131072];
    float* zs = (float*)smem;

    const int tid  = threadIdx.x;
    const int w    = tid >> 6, lane = tid & 63;
    const int quad = lane >> 4, l16 = lane & 15;
    const int h    = w >> 2;            // K-half: 0 = X@W, 1 = H@R
    const int sp   = w & 3;             // spatial wave within half
    const int mw   = (sp & 1) * 64;     // wave row offset in tile
    const int nw   = (sp >> 1) * 64;    // wave col offset in tile
    const int m0   = blockIdx.y * BM;
    const int q0   = blockIdx.x * BN;
    const int th   = tid & 255;         // thread id within half's 256-group
    const int wbase = (w & 3) * 64;     // wave-uniform lane base within half

    const _Float16* Ag0 = h ? Hrec : X;       // rows m, cols [0,1024)
    const _Float16* Bg0 = WR + h * HID;       // rows q, cols h*1024 + [0,1024)

    floatx4 acc[4][4];
    #pragma unroll
    for (int a = 0; a < 4; ++a)
        #pragma unroll
        for (int b = 0; b < 4; ++b)
            #pragma unroll
            for (int e = 0; e < 4; ++e) acc[a][b][e] = 0.f;

// issue half-stage hb (4 loads: A granules hb*4..hb*4+3 for all 128 rows,
// then B granules hb*4..hb*4+3 for all 128 q). Issue order A,A,B,B.
#define STAGE_HALF(bufsel, kc_, hb) do {                                                \
        _Float16* As_ = (_Float16*)(smem + (bufsel) * 65536 + h * 32768);               \
        _Float16* Bs_ = As_ + 8192;                                                     \
        const _Float16* Agk = Ag0 + (kc_);                                              \
        const _Float16* Bgk = Bg0 + (kc_);                                              \
        _Pragma("unroll")                                                               \
        for (int i_ = 2 * (hb); i_ < 2 * (hb) + 2; ++i_) {                              \
            const int s_ = i_ * 256 + th;                                               \
            const int r_ = s_ & 127, gl_ = s_ >> 7;                                     \
            __builtin_amdgcn_global_load_lds(AS1(Agk + (size_t)(m0 + r_) * HID + gl_ * 8),\
                                             AS3(As_ + (i_ * 256 + wbase) * 8), 16, 0, 0);\
        }                                                                               \
        _Pragma("unroll")                                                               \
        for (int i_ = 2 * (hb); i_ < 2 * (hb) + 2; ++i_) {                              \
            const int s_ = i_ * 256 + th;                                               \
            const int q_ = s_ & 127, gl_ = s_ >> 7;                                     \
            __builtin_amdgcn_global_load_lds(AS1(Bgk + (size_t)(q0 + q_) * K2 + gl_ * 8),\
                                             AS3(Bs_ + (i_ * 256 + wbase) * 8), 16, 0, 0);\
        }                                                                               \
    } while (0)

// one k-slice (32 of K): 8 ds_read_b128 + 16 MFMA per wave. LDS layout is
// granule-major: element offset = (lg*128 + row) * 8.
#define COMPUTE_KS(bufsel, ks) do {                                                     \
        const _Float16* As_ = (const _Float16*)(smem + (bufsel) * 65536 + h * 32768);   \
        const _Float16* Bs_ = As_ + 8192;                                               \
        const int lg = (ks) * 4 + quad;                                                 \
        half8 bfrag[4];                                                                 \
        _Pragma("unroll")                                                               \
        for (int b = 0; b < 4; ++b)                                                     \
            bfrag[b] = *(const half8*)&Bs_[(lg * 128 + nw + b * 16 + l16) * 8];         \
        _Pragma("unroll")                                                               \
        for (int a = 0; a < 4; ++a) {                                                   \
            const half8 afrag = *(const half8*)&As_[(lg * 128 + mw + a * 16 + l16) * 8];\
            acc[a][0] = __builtin_amdgcn_mfma_f32_16x16x32_f16(afrag, bfrag[0], acc[a][0], 0, 0, 0);\
            acc[a][1] = __builtin_amdgcn_mfma_f32_16x16x32_f16(afrag, bfrag[1], acc[a][1], 0, 0, 0);\
            acc[a][2] = __builtin_amdgcn_mfma_f32_16x16x32_f16(afrag, bfrag[2], acc[a][2], 0, 0, 0);\
            acc[a][3] = __builtin_amdgcn_mfma_f32_16x16x32_f16(afrag, bfrag[3], acc[a][3], 0, 0, 0);\
        }                                                                               \
    } while (0)

#define PHASE(WAITN)                                                                    \
        asm volatile("s_waitcnt vmcnt(" #WAITN ")" ::: "memory");                       \
        __builtin_amdgcn_s_barrier();                                                   \
        __builtin_amdgcn_sched_barrier(0);

    // prologue: both halves of tile 0 (8 loads outstanding)
    STAGE_HALF(0, 0, 0);
    STAGE_HALF(0, 0, 1);

    #pragma unroll 2
    for (int ts = 0; ts < KITERS - 1; ++ts) {
        const int cur = ts & 1, nxt = cur ^ 1;
        const int kcn = (ts + 1) * BKH;
        // phase 1: tile ts k-slice 0 (its 4 loads are the oldest 4 of 8)
        PHASE(4)
        STAGE_HALF(nxt, kcn, 0);
        COMPUTE_KS(cur, 0);
        // phase 2: tile ts k-slice 1 (oldest 4 of {ts.H2, ts+1.H1})
        PHASE(4)
        STAGE_HALF(nxt, kcn, 1);
        COMPUTE_KS(cur, 1);
    }
    {   // peeled last iter (ts = KITERS-1, cur = 1): no prefetch, drain 4 -> 0
        PHASE(4)
        COMPUTE_KS(1, 0);
        PHASE(0)
        COMPUTE_KS(1, 1);
    }
    __syncthreads();   // all frag reads done before zs overwrites the buffers

    // ---- combine K-halves in zs. C/D layout: col = lane&15, row = quad*4 + reg
    if (h == 0) {
        #pragma unroll
        for (int a = 0; a < 4; ++a)
            #pragma unroll
            for (int b = 0; b < 4; ++b)
                #pragma unroll
                for (int e = 0; e < 4; ++e)
                    zs[(mw + a * 16 + quad * 4 + e) * ZLD + nw + b * 16 + l16] = acc[a][b][e];
    }
    __syncthreads();
    if (h == 1) {
        #pragma unroll
        for (int a = 0; a < 4; ++a)
            #pragma unroll
            for (int b = 0; b < 4; ++b)
                #pragma unroll
                for (int e = 0; e < 4; ++e)
                    zs[(mw + a * 16 + quad * 4 + e) * ZLD + nw + b * 16 + l16] += acc[a][b][e];
    }
    __syncthreads();

    // epilogue: block covers m in [m0,m0+128), n in [32*bx, 32*bx+32)
    const int nl = tid & 31;
    const int mb = tid >> 5;             // 0..15
    const int n  = blockIdx.x * 32 + nl;
    const float bi = bias_j[n];
    const float bf = bias_j[HID + n];
    const float bg = bias_j[2 * HID + n];
    const float bo = bias_j[3 * HID + n];
    #pragma unroll
    for (int mi = 0; mi < 8; ++mi) {
        const int ml = mb + mi * 16;
        const int m  = m0 + ml;
        const float4 z4 = *(const float4*)&zs[ml * ZLD + 4 * nl];
        const float zi = z4.x + bi;
        const float zf = z4.y + bf;
        const float zg = z4.z + bg;
        const float zo = z4.w + bo;
        const float ig = 1.f / (1.f + __expf(-zi));
        const float fg = 1.f / (1.f + __expf(-zf));
        const float gg = tanhf(zg);
        const float og = 1.f / (1.f + __expf(-zo));
        const size_t idx = (size_t)m * HID + n;
        const float c = fg * c_m[idx] + ig * gg;
        const float hh = og * tanhf(c);
        c_m[idx] = c;
        c_out[idx] = (_Float16)c;
        h_out[idx] = (_Float16)hh;
    }
#undef STAGE_HALF
#undef COMPUTE_KS
#undef PHASE
}

extern "C" void kernel_launch(void* const* d_in, const int* in_sizes, int n_in,
                              void* d_out, int out_size, void* d_ws, size_t ws_size,
                              hipStream_t stream) {
    const float* inputs     = (const float*)d_in[0]; // [30,256,1024]
    const float* kernel_    = (const float*)d_in[1]; // [4,1024,4096]
    const float* rec_kernel = (const float*)d_in[2]; // [4,1024,4096]
    const float* bias       = (const float*)d_in[3]; // [4,4096]
    float* out = (float*)d_out;                      // [256,1024]

    char* ws = (char*)d_ws;
    _Float16* WRt      = (_Float16*)(ws);                 // 67,108,864 B
    _Float16* Xf       = (_Float16*)(ws + 67108864);      // 15,728,640 B
    float*    c_master = (float*)   (ws + 82837504);      //  4,194,304 B
    _Float16* c_f16    = (_Float16*)(ws + 87031808);      //  4,194,304 B (2 parity)
    _Float16* h_f16    = (_Float16*)(ws + 91226112);      //  2,097,152 B
    // total 93,323,264 B (unchanged footprint, known to fit)

    const size_t BH = (size_t)BATCH * HID;

    hipMemsetAsync(c_master, 0, LAYERS * BH * sizeof(float), stream);
    hipMemsetAsync(h_f16, 0, LAYERS * BH * sizeof(_Float16), stream);

    transpose_weights<<<dim3(N4H / 64, HID / 128, LAYERS), 256, 0, stream>>>(
        kernel_, WRt, 0);
    transpose_weights<<<dim3(N4H / 64, HID / 128, LAYERS), 256, 0, stream>>>(
        rec_kernel, WRt, 1);
    cvt_inputs<<<(T_STEPS * BATCH * HID) / 8 / 256, 256, 0, stream>>>(inputs, Xf);

    for (int d = 0; d < T_STEPS + LAYERS - 1; ++d) {
        const int jlo = (d - (T_STEPS - 1)) > 0 ? (d - (T_STEPS - 1)) : 0;
        const int jhi = d < (LAYERS - 1) ? d : (LAYERS - 1);
        const int nc  = jhi - jlo + 1;
        int pt = 0, pj = 0;
        for (int zz = 0; zz < nc; ++zz) {
            const int jj = jlo + zz, tt = d - jj;
            pt |= tt << (8 * zz);
            pj |= jj << (8 * zz);
        }
        lstm_diag<<<dim3(N4H / BN, BATCH / BM, nc), 512, 0, stream>>>(
            Xf, c_f16, h_f16, WRt, bias, c_master, d, pt, pj);
    }

    hipMemcpyAsync(out, c_master + 3 * BH, BH * sizeof(float),
                   hipMemcpyDeviceToDevice, stream);
}

// Round 7
// 1140.398 us; speedup vs baseline: 1.4266x; 1.4266x over previous
//
#include <hip/hip_runtime.h>
#include <hip/hip_fp16.h>

typedef _Float16 half8 __attribute__((ext_vector_type(8)));
typedef float floatx4 __attribute__((ext_vector_type(4)));

#define T_STEPS 30
#define BATCH   256
#define HID     1024
#define LAYERS  4
#define N4H     4096
#define K2      2048

#define BM 128
#define BN 64
#define BK 64       // K per iteration (full K=2048 per wave, no split-K)
#define KITERS 32   // 2048 / BK
#define ZLD 68      // zs row stride (f32), multiple of 4 for float4 reads

#define AS1(p) ((const __attribute__((address_space(1))) void*)(p))
#define AS3(p) ((__attribute__((address_space(3))) void*)(p))

// ---------- one-time prep: weights [L][H][4H] f32 -> WRt [L][4096 q][2048 k] f16
// q = 4n + gate; W in k[0,1024), R in k[1024,2048).
// v4: two 64x64 k-tiles per block (8 float4 loads in flight), volatile scalar
// LDS stores (prevents misaligned ds_write_b128 merge -> 2-way banks, free).
__global__ void transpose_weights(const float* __restrict__ src_all,
                                  _Float16* __restrict__ wrt, int mat) {
    __shared__ float tile[2][64][65];
    const int j = blockIdx.z;
    const float* src = src_all + (size_t)j * HID * N4H;
    _Float16* dst = wrt + (size_t)j * N4H * K2 + mat * HID;
    const int c0 = blockIdx.x * 64;     // source column tile (over 4H)
    const int k0 = blockIdx.y * 128;    // source row pair-tile (over H = k dim)
    const int t = threadIdx.x;          // 256 flat
    const int c4 = (t & 15) * 4, lr = t >> 4;
    #pragma unroll
    for (int tt = 0; tt < 2; ++tt)
        #pragma unroll
        for (int i = 0; i < 4; ++i) {
            const float4 v = *(const float4*)(src + (size_t)(k0 + tt * 64 + lr + i * 16) * N4H + c0 + c4);
            volatile float* tw = &tile[tt][lr + i * 16][c4];
            tw[0] = v.x; tw[1] = v.y; tw[2] = v.z; tw[3] = v.w;
        }
    __syncthreads();
    const int kg = t & 7, cl0 = t >> 3;   // 8 k-granules x 32 c-lanes
    #pragma unroll
    for (int tt = 0; tt < 2; ++tt)
        #pragma unroll
        for (int i = 0; i < 2; ++i) {
            const int cp = cl0 + i * 32;
            const int c = c0 + cp;
            const int q = ((c & (HID - 1)) << 2) | (c >> 10); // q = 4n + gate
            half8 v;
            #pragma unroll
            for (int jj = 0; jj < 8; ++jj)
                v[jj] = (_Float16)tile[tt][kg * 8 + jj][cp];
            *(half8*)(dst + (size_t)q * K2 + k0 + tt * 64 + kg * 8) = v;
        }
}

// ---------- inputs f32 -> f16
__global__ void cvt_inputs(const float* __restrict__ in, _Float16* __restrict__ out) {
    const size_t i = ((size_t)blockIdx.x * 256 + threadIdx.x) * 8;
    const float4 a = *(const float4*)(in + i);
    const float4 b = *(const float4*)(in + i + 4);
    half8 v;
    v[0] = (_Float16)a.x; v[1] = (_Float16)a.y; v[2] = (_Float16)a.z; v[3] = (_Float16)a.w;
    v[4] = (_Float16)b.x; v[5] = (_Float16)b.y; v[6] = (_Float16)b.z; v[7] = (_Float16)b.w;
    *(half8*)(out + i) = v;
}

// ---------- diagonal-batched fused LSTM cells, v6
// Occupancy-first: block tile 128m x 64n, 512 threads = 8 waves (4m x 2n),
// each wave 32x32 over the FULL K=2048 (no split-K, no zs combine pass).
// LDS = 2 x 24 KB stage buffers (A 128x64 f16 = 16 KB, B 64x64 f16 = 8 KB),
// zs (128 x 68 f32 = 34.8 KB) overlays -> 48 KB/block -> 2-3 blocks/CU
// resident (grid 512 at nc=4). Cross-block overlap (m114) hides the per-iter
// vmcnt(0) drain at __syncthreads - the R1-proven loop structure is kept.
// Staging: R1's row-major XOR-8 granule swizzle (slot s -> r=s>>3,
// g=(s&7)^(r&7)); 8 consecutive lanes cover one row's 8 granules = 128 B
// contiguous global reads (v5's k-major 2KB-stride scatter was the R6
// regression: 8x request-rate inflation).
__global__ __launch_bounds__(512, 4) void lstm_diag(
    const _Float16* __restrict__ Xf,      // [30][256][1024] f16
    _Float16*       __restrict__ c_act,   // [2 parity][4][256][1024] f16
    _Float16*       __restrict__ h_act,   // [4][256][1024] f16
    const _Float16* __restrict__ WRt,     // [4][4096][2048] f16
    const float*    __restrict__ bias,    // [4][4096] f32 gate-major
    float*          __restrict__ c_master,// [4][256][1024] f32
    int diag, int packed_t, int packed_j)
{
    const int z = blockIdx.z;
    const int t = (packed_t >> (8 * z)) & 255;
    const int j = (packed_j >> (8 * z)) & 255;
    const size_t BH = (size_t)BATCH * HID;

    const _Float16* X    = (j == 0) ? (Xf + (size_t)t * BH)
                                    : (c_act + ((size_t)((diag - 1) & 1) * LAYERS + (j - 1)) * BH);
    const _Float16* Hrec = h_act + (size_t)j * BH;
    const _Float16* WR   = WRt + (size_t)j * N4H * K2;
    const float* bias_j  = bias + (size_t)j * N4H;
    float* c_m           = c_master + (size_t)j * BH;
    _Float16* c_out      = c_act + ((size_t)(diag & 1) * LAYERS + j) * BH;
    _Float16* h_out      = h_act + (size_t)j * BH;

    // LDS: 2 stage buffers x 24576 B: A 128x64 f16 (16384 B) | B 64x64 f16
    // (8192 B). zs (128 x ZLD f32 = 34816 B) overlays after the K loop.
    __shared__ __align__(16) char smem[49152];
    float* zs = (float*)smem;

    const int tid  = threadIdx.x;
    const int w    = tid >> 6, lane = tid & 63;
    const int quad = lane >> 4, l16 = lane & 15;
    const int mw   = (w & 3) * 32;      // wave row offset in tile
    const int nw   = (w >> 2) * 32;     // wave col offset in tile
    const int m0   = blockIdx.y * BM;
    const int q0   = blockIdx.x * BN;

    floatx4 acc[2][2];
    #pragma unroll
    for (int a = 0; a < 2; ++a)
        #pragma unroll
        for (int b = 0; b < 2; ++b)
            #pragma unroll
            for (int e = 0; e < 4; ++e) acc[a][b][e] = 0.f;

// stage one K-tile: A 1024 granules (2 loads/thread), B 512 granules (1).
// Row-major XOR-8: slot s -> (r=s>>3, g=(s&7)^(r&7)); 128 B per 8 lanes.
#define STAGE(bufsel, kc_) do {                                                         \
        _Float16* As_ = (_Float16*)(smem + (bufsel) * 24576);                           \
        _Float16* Bs_ = As_ + 8192;                                                     \
        const _Float16* Agk = ((kc_) < HID) ? (X + (kc_)) : (Hrec + ((kc_) - HID));     \
        const _Float16* Bgk = WR + (kc_);                                               \
        _Pragma("unroll")                                                               \
        for (int i_ = 0; i_ < 2; ++i_) {                                                \
            const int slot = i_ * 512 + tid;                                            \
            const int r_ = slot >> 3;                                                   \
            const int g_ = (slot & 7) ^ (r_ & 7);                                       \
            __builtin_amdgcn_global_load_lds(AS1(Agk + (size_t)(m0 + r_) * HID + g_ * 8),\
                                             AS3(As_ + (i_ * 512 + w * 64) * 8), 16, 0, 0);\
        }                                                                               \
        {                                                                               \
            const int slot = tid;                                                       \
            const int q_ = slot >> 3;                                                   \
            const int g_ = (slot & 7) ^ (q_ & 7);                                       \
            __builtin_amdgcn_global_load_lds(AS1(Bgk + (size_t)(q0 + q_) * K2 + g_ * 8), \
                                             AS3(Bs_ + (w * 64) * 8), 16, 0, 0);        \
        }                                                                               \
    } while (0)

// one K-tile: 2 k-slices x {4 ds_read_b128 + 4 MFMA} per wave.
#define COMPUTE(bufsel) do {                                                            \
        const _Float16* As_ = (const _Float16*)(smem + (bufsel) * 24576);               \
        const _Float16* Bs_ = As_ + 8192;                                               \
        _Pragma("unroll")                                                               \
        for (int ks = 0; ks < 2; ++ks) {                                                \
            const int gq = ks * 4 + quad;                                               \
            half8 bfrag[2];                                                             \
            _Pragma("unroll")                                                           \
            for (int b = 0; b < 2; ++b) {                                               \
                const int q = nw + b * 16 + l16;                                        \
                bfrag[b] = *(const half8*)&Bs_[((q << 3) + (gq ^ (q & 7))) * 8];        \
            }                                                                           \
            _Pragma("unroll")                                                           \
            for (int a = 0; a < 2; ++a) {                                               \
                const int r = mw + a * 16 + l16;                                        \
                const half8 afrag = *(const half8*)&As_[((r << 3) + (gq ^ (r & 7))) * 8];\
                acc[a][0] = __builtin_amdgcn_mfma_f32_16x16x32_f16(afrag, bfrag[0], acc[a][0], 0, 0, 0);\
                acc[a][1] = __builtin_amdgcn_mfma_f32_16x16x32_f16(afrag, bfrag[1], acc[a][1], 0, 0, 0);\
            }                                                                           \
        }                                                                               \
    } while (0)

    STAGE(0, 0);
    __syncthreads();
    #pragma unroll 2
    for (int ts = 0; ts < KITERS; ++ts) {
        const int cur = ts & 1;
        if (ts + 1 < KITERS) STAGE(cur ^ 1, (ts + 1) * BK);  // prefetch next tile
        COMPUTE(cur);
        __syncthreads();   // drains vmcnt (next buf ready) + protects cur buf
    }
    // (final __syncthreads of the loop also orders frag reads before zs writes)

    // ---- write z to zs. C/D layout: col = lane&15, row = quad*4 + reg
    #pragma unroll
    for (int a = 0; a < 2; ++a)
        #pragma unroll
        for (int b = 0; b < 2; ++b)
            #pragma unroll
            for (int e = 0; e < 4; ++e)
                zs[(mw + a * 16 + quad * 4 + e) * ZLD + nw + b * 16 + l16] = acc[a][b][e];
    __syncthreads();

    // epilogue: block covers m in [m0,m0+128), hidden n in [16*bx, 16*bx+16)
    const int nl = tid & 15;
    const int mb = tid >> 4;             // 0..31
    const int n  = blockIdx.x * 16 + nl;
    const float bi = bias_j[n];
    const float bf = bias_j[HID + n];
    const float bg = bias_j[2 * HID + n];
    const float bo = bias_j[3 * HID + n];
    #pragma unroll
    for (int mi = 0; mi < 4; ++mi) {
        const int ml = mb + mi * 32;
        const int m  = m0 + ml;
        const float4 z4 = *(const float4*)&zs[ml * ZLD + 4 * nl];
        const float zi = z4.x + bi;
        const float zf = z4.y + bf;
        const float zg = z4.z + bg;
        const float zo = z4.w + bo;
        const float ig = 1.f / (1.f + __expf(-zi));
        const float fg = 1.f / (1.f + __expf(-zf));
        const float gg = tanhf(zg);
        const float og = 1.f / (1.f + __expf(-zo));
        const size_t idx = (size_t)m * HID + n;
        const float c = fg * c_m[idx] + ig * gg;
        const float hh = og * tanhf(c);
        c_m[idx] = c;
        c_out[idx] = (_Float16)c;
        h_out[idx] = (_Float16)hh;
    }
#undef STAGE
#undef COMPUTE
}

extern "C" void kernel_launch(void* const* d_in, const int* in_sizes, int n_in,
                              void* d_out, int out_size, void* d_ws, size_t ws_size,
                              hipStream_t stream) {
    const float* inputs     = (const float*)d_in[0]; // [30,256,1024]
    const float* kernel_    = (const float*)d_in[1]; // [4,1024,4096]
    const float* rec_kernel = (const float*)d_in[2]; // [4,1024,4096]
    const float* bias       = (const float*)d_in[3]; // [4,4096]
    float* out = (float*)d_out;                      // [256,1024]

    char* ws = (char*)d_ws;
    _Float16* WRt      = (_Float16*)(ws);                 // 67,108,864 B
    _Float16* Xf       = (_Float16*)(ws + 67108864);      // 15,728,640 B
    float*    c_master = (float*)   (ws + 82837504);      //  4,194,304 B
    _Float16* c_f16    = (_Float16*)(ws + 87031808);      //  4,194,304 B (2 parity)
    _Float16* h_f16    = (_Float16*)(ws + 91226112);      //  2,097,152 B
    // total 93,323,264 B (unchanged footprint, known to fit)

    const size_t BH = (size_t)BATCH * HID;

    hipMemsetAsync(c_master, 0, LAYERS * BH * sizeof(float), stream);
    hipMemsetAsync(h_f16, 0, LAYERS * BH * sizeof(_Float16), stream);

    transpose_weights<<<dim3(N4H / 64, HID / 128, LAYERS), 256, 0, stream>>>(
        kernel_, WRt, 0);
    transpose_weights<<<dim3(N4H / 64, HID / 128, LAYERS), 256, 0, stream>>>(
        rec_kernel, WRt, 1);
    cvt_inputs<<<(T_STEPS * BATCH * HID) / 8 / 256, 256, 0, stream>>>(inputs, Xf);

    for (int d = 0; d < T_STEPS + LAYERS - 1; ++d) {
        const int jlo = (d - (T_STEPS - 1)) > 0 ? (d - (T_STEPS - 1)) : 0;
        const int jhi = d < (LAYERS - 1) ? d : (LAYERS - 1);
        const int nc  = jhi - jlo + 1;
        int pt = 0, pj = 0;
        for (int zz = 0; zz < nc; ++zz) {
            const int jj = jlo + zz, tt = d - jj;
            pt |= tt << (8 * zz);
            pj |= jj << (8 * zz);
        }
        lstm_diag<<<dim3(N4H / BN, BATCH / BM, nc), 512, 0, stream>>>(
            Xf, c_f16, h_f16, WRt, bias, c_master, d, pt, pj);
    }

    hipMemcpyAsync(out, c_master + 3 * BH, BH * sizeof(float),
                   hipMemcpyDeviceToDevice, stream);
}

// Round 8
// 1045.796 us; speedup vs baseline: 1.5556x; 1.0905x over previous
//
#include <hip/hip_runtime.h>
#include <hip/hip_fp16.h>

typedef _Float16 half8 __attribute__((ext_vector_type(8)));
typedef float floatx4 __attribute__((ext_vector_type(4)));

#define T_STEPS 30
#define BATCH   256
#define HID     1024
#define LAYERS  4
#define N4H     4096
#define K2      2048

#define BM 128
#define BN 128
#define BK 64       // K per iteration (full K=2048 per block, no split-K)
#define KITERS 32   // 2048 / BK
#define ZLD 132     // zs row stride (f32), multiple of 4 for float4 reads

#define AS1(p) ((const __attribute__((address_space(1))) void*)(p))
#define AS3(p) ((__attribute__((address_space(3))) void*)(p))

// ---------- one-time prep: weights [L][H][4H] f32 -> WRt [L][4096 q][2048 k] f16
// q = 4n + gate; W in k[0,1024), R in k[1024,2048).
// v4: two 64x64 k-tiles per block (8 float4 loads in flight), volatile scalar
// LDS stores (prevents misaligned ds_write_b128 merge -> 2-way banks, free).
__global__ void transpose_weights(const float* __restrict__ src_all,
                                  _Float16* __restrict__ wrt, int mat) {
    __shared__ float tile[2][64][65];
    const int j = blockIdx.z;
    const float* src = src_all + (size_t)j * HID * N4H;
    _Float16* dst = wrt + (size_t)j * N4H * K2 + mat * HID;
    const int c0 = blockIdx.x * 64;     // source column tile (over 4H)
    const int k0 = blockIdx.y * 128;    // source row pair-tile (over H = k dim)
    const int t = threadIdx.x;          // 256 flat
    const int c4 = (t & 15) * 4, lr = t >> 4;
    #pragma unroll
    for (int tt = 0; tt < 2; ++tt)
        #pragma unroll
        for (int i = 0; i < 4; ++i) {
            const float4 v = *(const float4*)(src + (size_t)(k0 + tt * 64 + lr + i * 16) * N4H + c0 + c4);
            volatile float* tw = &tile[tt][lr + i * 16][c4];
            tw[0] = v.x; tw[1] = v.y; tw[2] = v.z; tw[3] = v.w;
        }
    __syncthreads();
    const int kg = t & 7, cl0 = t >> 3;   // 8 k-granules x 32 c-lanes
    #pragma unroll
    for (int tt = 0; tt < 2; ++tt)
        #pragma unroll
        for (int i = 0; i < 2; ++i) {
            const int cp = cl0 + i * 32;
            const int c = c0 + cp;
            const int q = ((c & (HID - 1)) << 2) | (c >> 10); // q = 4n + gate
            half8 v;
            #pragma unroll
            for (int jj = 0; jj < 8; ++jj)
                v[jj] = (_Float16)tile[tt][kg * 8 + jj][cp];
            *(half8*)(dst + (size_t)q * K2 + k0 + tt * 64 + kg * 8) = v;
        }
}

// ---------- inputs f32 -> f16
__global__ void cvt_inputs(const float* __restrict__ in, _Float16* __restrict__ out) {
    const size_t i = ((size_t)blockIdx.x * 256 + threadIdx.x) * 8;
    const float4 a = *(const float4*)(in + i);
    const float4 b = *(const float4*)(in + i + 4);
    half8 v;
    v[0] = (_Float16)a.x; v[1] = (_Float16)a.y; v[2] = (_Float16)a.z; v[3] = (_Float16)a.w;
    v[4] = (_Float16)b.x; v[5] = (_Float16)b.y; v[6] = (_Float16)b.z; v[7] = (_Float16)b.w;
    *(half8*)(out + i) = v;
}

// ---------- diagonal-batched fused LSTM cells, v7
// R4's proven geometry (block tile 128m x 128n, 64 MB/cell L2-fill, 16 MFMA +
// 12 ds_read per wave-iter) with ONE change: triple-buffered staging at
// prefetch distance 2 + counted vmcnt(4) (T4) so the global_load_lds stream
// never drains to 0 inside the K loop (R4 drained every iter = 16 exposed
// pulse heads). Split-K dropped: 8 waves = 2m x 4n, each 64x32 over the full
// K=2048 (same per-iter instruction mix as R4's halves; no zs combine pass).
//
// Sync ledger: STAGE = 4 loads/thread (A 2, B 2). Prologue stages tiles 0,1
// (8 outstanding). Iter ts: wait vmcnt(4) -> tile ts's 4 landed (in-order
// retire); s_barrier extends to all waves; stage tile ts+2 into buf
// (ts+2)%3; compute buf ts%3. WAR safe: a wave's ds_reads of buf b complete
// before it reaches the next barrier (the MFMAs consuming them are
// program-prior and force lgkmcnt waits), so post-barrier staging into a
// buffer last read one iteration earlier cannot race. Final iter drains 0.
// Pattern correctness proven in R2/R5 (both passed absmax).
__global__ __launch_bounds__(512) void lstm_diag(
    const _Float16* __restrict__ Xf,      // [30][256][1024] f16
    _Float16*       __restrict__ c_act,   // [2 parity][4][256][1024] f16
    _Float16*       __restrict__ h_act,   // [4][256][1024] f16
    const _Float16* __restrict__ WRt,     // [4][4096][2048] f16
    const float*    __restrict__ bias,    // [4][4096] f32 gate-major
    float*          __restrict__ c_master,// [4][256][1024] f32
    int diag, int packed_t, int packed_j)
{
    const int z = blockIdx.z;
    const int t = (packed_t >> (8 * z)) & 255;
    const int j = (packed_j >> (8 * z)) & 255;
    const size_t BH = (size_t)BATCH * HID;

    const _Float16* X    = (j == 0) ? (Xf + (size_t)t * BH)
                                    : (c_act + ((size_t)((diag - 1) & 1) * LAYERS + (j - 1)) * BH);
    const _Float16* Hrec = h_act + (size_t)j * BH;
    const _Float16* WR   = WRt + (size_t)j * N4H * K2;
    const float* bias_j  = bias + (size_t)j * N4H;
    float* c_m           = c_master + (size_t)j * BH;
    _Float16* c_out      = c_act + ((size_t)(diag & 1) * LAYERS + j) * BH;
    _Float16* h_out      = h_act + (size_t)j * BH;

    // LDS: 3 stage buffers x 32768 B: A 128x64 f16 (16 KB) | B 128x64 f16
    // (16 KB). zs (128 x ZLD f32 = 67584 B) overlays bufs after the K loop.
    __shared__ __align__(16) char smem[98304];
    float* zs = (float*)smem;

    const int tid  = threadIdx.x;
    const int w    = tid >> 6, lane = tid & 63;
    const int quad = lane >> 4, l16 = lane & 15;
    const int mw   = (w & 1) * 64;      // wave row offset in tile
    const int nw   = (w >> 1) * 32;     // wave col offset in tile
    const int m0   = blockIdx.y * BM;
    const int q0   = blockIdx.x * BN;

    floatx4 acc[4][2];
    #pragma unroll
    for (int a = 0; a < 4; ++a)
        #pragma unroll
        for (int b = 0; b < 2; ++b)
            #pragma unroll
            for (int e = 0; e < 4; ++e) acc[a][b][e] = 0.f;

// stage one K-tile: A 1024 granules (2 loads/thread), B 1024 (2 loads).
// Row-major XOR-8: slot s -> (r=s>>3, g=(s&7)^(r&7)); 128 B per 8 lanes.
#define STAGE(bufsel, kc_) do {                                                         \
        _Float16* As_ = (_Float16*)(smem + (bufsel) * 32768);                           \
        _Float16* Bs_ = As_ + 8192;                                                     \
        const _Float16* Agk = ((kc_) < HID) ? (X + (kc_)) : (Hrec + ((kc_) - HID));     \
        const _Float16* Bgk = WR + (kc_);                                               \
        _Pragma("unroll")                                                               \
        for (int i_ = 0; i_ < 2; ++i_) {                                                \
            const int slot = i_ * 512 + tid;                                            \
            const int r_ = slot >> 3;                                                   \
            const int g_ = (slot & 7) ^ (r_ & 7);                                       \
            __builtin_amdgcn_global_load_lds(AS1(Agk + (size_t)(m0 + r_) * HID + g_ * 8),\
                                             AS3(As_ + (i_ * 512 + w * 64) * 8), 16, 0, 0);\
        }                                                                               \
        _Pragma("unroll")                                                               \
        for (int i_ = 0; i_ < 2; ++i_) {                                                \
            const int slot = i_ * 512 + tid;                                            \
            const int q_ = slot >> 3;                                                   \
            const int g_ = (slot & 7) ^ (q_ & 7);                                       \
            __builtin_amdgcn_global_load_lds(AS1(Bgk + (size_t)(q0 + q_) * K2 + g_ * 8), \
                                             AS3(Bs_ + (i_ * 512 + w * 64) * 8), 16, 0, 0);\
        }                                                                               \
    } while (0)

// one K-tile: 2 k-slices x {4 A-frag + 2 B-frag ds_read_b128, 8 MFMA}.
#define COMPUTE(bufsel) do {                                                            \
        const _Float16* As_ = (const _Float16*)(smem + (bufsel) * 32768);               \
        const _Float16* Bs_ = As_ + 8192;                                               \
        _Pragma("unroll")                                                               \
        for (int ks = 0; ks < 2; ++ks) {                                                \
            const int gq = ks * 4 + quad;                                               \
            half8 bfrag[2];                                                             \
            _Pragma("unroll")                                                           \
            for (int b = 0; b < 2; ++b) {                                               \
                const int q = nw + b * 16 + l16;                                        \
                bfrag[b] = *(const half8*)&Bs_[((q << 3) + (gq ^ (q & 7))) * 8];        \
            }                                                                           \
            _Pragma("unroll")                                                           \
            for (int a = 0; a < 4; ++a) {                                               \
                const int r = mw + a * 16 + l16;                                        \
                const half8 afrag = *(const half8*)&As_[((r << 3) + (gq ^ (r & 7))) * 8];\
                acc[a][0] = __builtin_amdgcn_mfma_f32_16x16x32_f16(afrag, bfrag[0], acc[a][0], 0, 0, 0);\
                acc[a][1] = __builtin_amdgcn_mfma_f32_16x16x32_f16(afrag, bfrag[1], acc[a][1], 0, 0, 0);\
            }                                                                           \
        }                                                                               \
    } while (0)

    STAGE(0, 0);
    STAGE(1, BK);
    int cur = 0;                       // buffer of tile ts
    for (int ts = 0; ts < KITERS - 1; ++ts) {
        asm volatile("s_waitcnt vmcnt(4)" ::: "memory");   // tile ts landed
        __builtin_amdgcn_s_barrier();
        if (ts + 2 < KITERS) {
            int nx = cur + 2; if (nx >= 3) nx -= 3;
            STAGE(nx, (ts + 2) * BK);                      // keep 8 in flight
        }
        COMPUTE(cur);
        ++cur; if (cur == 3) cur = 0;
    }
    asm volatile("s_waitcnt vmcnt(0)" ::: "memory");       // last tile landed
    __builtin_amdgcn_s_barrier();
    COMPUTE(cur);
    __syncthreads();   // all frag reads done before zs overwrites the buffers

    // ---- write z to zs. C/D layout: col = lane&15, row = quad*4 + reg
    #pragma unroll
    for (int a = 0; a < 4; ++a)
        #pragma unroll
        for (int b = 0; b < 2; ++b)
            #pragma unroll
            for (int e = 0; e < 4; ++e)
                zs[(mw + a * 16 + quad * 4 + e) * ZLD + nw + b * 16 + l16] = acc[a][b][e];
    __syncthreads();

    // epilogue: block covers m in [m0,m0+128), hidden n in [32*bx, 32*bx+32)
    const int nl = tid & 31;
    const int mb = tid >> 5;             // 0..15
    const int n  = blockIdx.x * 32 + nl;
    const float bi = bias_j[n];
    const float bf = bias_j[HID + n];
    const float bg = bias_j[2 * HID + n];
    const float bo = bias_j[3 * HID + n];
    #pragma unroll
    for (int mi = 0; mi < 8; ++mi) {
        const int ml = mb + mi * 16;
        const int m  = m0 + ml;
        const float4 z4 = *(const float4*)&zs[ml * ZLD + 4 * nl];
        const float zi = z4.x + bi;
        const float zf = z4.y + bf;
        const float zg = z4.z + bg;
        const float zo = z4.w + bo;
        const float ig = 1.f / (1.f + __expf(-zi));
        const float fg = 1.f / (1.f + __expf(-zf));
        const float gg = tanhf(zg);
        const float og = 1.f / (1.f + __expf(-zo));
        const size_t idx = (size_t)m * HID + n;
        const float c = fg * c_m[idx] + ig * gg;
        const float hh = og * tanhf(c);
        c_m[idx] = c;
        c_out[idx] = (_Float16)c;
        h_out[idx] = (_Float16)hh;
    }
#undef STAGE
#undef COMPUTE
}

extern "C" void kernel_launch(void* const* d_in, const int* in_sizes, int n_in,
                              void* d_out, int out_size, void* d_ws, size_t ws_size,
                              hipStream_t stream) {
    const float* inputs     = (const float*)d_in[0]; // [30,256,1024]
    const float* kernel_    = (const float*)d_in[1]; // [4,1024,4096]
    const float* rec_kernel = (const float*)d_in[2]; // [4,1024,4096]
    const float* bias       = (const float*)d_in[3]; // [4,4096]
    float* out = (float*)d_out;                      // [256,1024]

    char* ws = (char*)d_ws;
    _Float16* WRt      = (_Float16*)(ws);                 // 67,108,864 B
    _Float16* Xf       = (_Float16*)(ws + 67108864);      // 15,728,640 B
    float*    c_master = (float*)   (ws + 82837504);      //  4,194,304 B
    _Float16* c_f16    = (_Float16*)(ws + 87031808);      //  4,194,304 B (2 parity)
    _Float16* h_f16    = (_Float16*)(ws + 91226112);      //  2,097,152 B
    // total 93,323,264 B (unchanged footprint, known to fit)

    const size_t BH = (size_t)BATCH * HID;

    hipMemsetAsync(c_master, 0, LAYERS * BH * sizeof(float), stream);
    hipMemsetAsync(h_f16, 0, LAYERS * BH * sizeof(_Float16), stream);

    transpose_weights<<<dim3(N4H / 64, HID / 128, LAYERS), 256, 0, stream>>>(
        kernel_, WRt, 0);
    transpose_weights<<<dim3(N4H / 64, HID / 128, LAYERS), 256, 0, stream>>>(
        rec_kernel, WRt, 1);
    cvt_inputs<<<(T_STEPS * BATCH * HID) / 8 / 256, 256, 0, stream>>>(inputs, Xf);

    for (int d = 0; d < T_STEPS + LAYERS - 1; ++d) {
        const int jlo = (d - (T_STEPS - 1)) > 0 ? (d - (T_STEPS - 1)) : 0;
        const int jhi = d < (LAYERS - 1) ? d : (LAYERS - 1);
        const int nc  = jhi - jlo + 1;
        int pt = 0, pj = 0;
        for (int zz = 0; zz < nc; ++zz) {
            const int jj = jlo + zz, tt = d - jj;
            pt |= tt << (8 * zz);
            pj |= jj << (8 * zz);
        }
        lstm_diag<<<dim3(N4H / BN, BATCH / BM, nc), 512, 0, stream>>>(
            Xf, c_f16, h_f16, WRt, bias, c_master, d, pt, pj);
    }

    hipMemcpyAsync(out, c_master + 3 * BH, BH * sizeof(float),
                   hipMemcpyDeviceToDevice, stream);
}